// Round 7
// baseline (321.589 us; speedup 1.0000x reference)
//
#include <hip/hip_runtime.h>
#include <math.h>

// ---------------------------------------------------------------------------
// Deformable transformer layer, MI355X round-7:
//  - GEMM: B staged in LDS (16 KB, 8-chunk conflict-free swizzle), A loaded
//    DIRECTLY from global as per-lane short8 gathers (no barrier dependency,
//    L2/L3-resident) -> halved LDS + staging, 8 blocks/CU, drains overlap.
//    Operand-swapped MFMA + LDS-staged coalesced epilogue (16-row bands).
//  - two-phase deform sampling (prep tables + lean gather).
// B=2, Nq=8192, C=256, HEADS=8, dh=32, LEVELS=3, POINTS=4, MLP=4
// ---------------------------------------------------------------------------

typedef short short8 __attribute__((ext_vector_type(8)));
typedef short s16x4 __attribute__((ext_vector_type(4)));
typedef __bf16 bf16x8 __attribute__((ext_vector_type(8)));
typedef float f32x4 __attribute__((ext_vector_type(4)));

__device__ __forceinline__ short f2b(float f) {
  unsigned u = __builtin_bit_cast(unsigned, f);
  u += 0x7fffu + ((u >> 16) & 1u);   // RNE to bf16
  return (short)(u >> 16);
}
__device__ __forceinline__ float b2f(short s) {
  unsigned u = ((unsigned)(unsigned short)s) << 16;
  return __builtin_bit_cast(float, u);
}
__device__ __forceinline__ void b8f(short8 s, float* f) {
  const uint4 u = __builtin_bit_cast(uint4, s);
  f[0] = __builtin_bit_cast(float, u.x << 16);
  f[1] = __builtin_bit_cast(float, u.x & 0xffff0000u);
  f[2] = __builtin_bit_cast(float, u.y << 16);
  f[3] = __builtin_bit_cast(float, u.y & 0xffff0000u);
  f[4] = __builtin_bit_cast(float, u.z << 16);
  f[5] = __builtin_bit_cast(float, u.z & 0xffff0000u);
  f[6] = __builtin_bit_cast(float, u.w << 16);
  f[7] = __builtin_bit_cast(float, u.w & 0xffff0000u);
}

__device__ __forceinline__ f32x4 mfma16(short8 a, short8 b, f32x4 c) {
  return __builtin_amdgcn_mfma_f32_16x16x32_bf16(
      __builtin_bit_cast(bf16x8, a), __builtin_bit_cast(bf16x8, b), c, 0, 0, 0);
}

typedef __attribute__((address_space(3))) unsigned int lds_u32;
typedef const __attribute__((address_space(1))) unsigned int glb_u32;
__device__ __forceinline__ void glds16(const void* g, void* l) {
  __builtin_amdgcn_global_load_lds((glb_u32*)g, (lds_u32*)l, 16, 0, 0);
}

__device__ __forceinline__ float gelu1(float v) {
  return 0.5f * v * (1.f + erff(v * 0.70710678118654752f));
}

// ---------------------------------------------------------------------------
// Weight convert + transpose: Wt[n][k] bf16 from W[k][n] fp32.
// ---------------------------------------------------------------------------
__global__ __launch_bounds__(256) void wconvert(
    const float* __restrict__ Wo, const float* __restrict__ Wa,
    const float* __restrict__ Wv, const float* __restrict__ Wp,
    const float* __restrict__ Wf1, const float* __restrict__ Wf2,
    short* __restrict__ t_oa, short* __restrict__ t_v, short* __restrict__ t_p,
    short* __restrict__ t_f1, short* __restrict__ t_f2)
{
  __shared__ float tile[32][33];
  int K, N, noff; const float* src; short* dst;
  switch (blockIdx.y) {
    case 0: src = Wo;      dst = t_oa; K = 256;  N = 192;  noff = 0;   break;
    case 1: src = Wa;      dst = t_oa; K = 256;  N = 96;   noff = 192; break;
    case 2: src = nullptr; dst = t_oa; K = 256;  N = 96;   noff = 288; break;
    case 3: src = Wv;      dst = t_v;  K = 256;  N = 256;  noff = 0;   break;
    case 4: src = Wp;      dst = t_p;  K = 256;  N = 256;  noff = 0;   break;
    case 5: src = Wf1;     dst = t_f1; K = 256;  N = 1024; noff = 0;   break;
    default: src = Wf2;    dst = t_f2; K = 1024; N = 256;  noff = 0;   break;
  }
  const int tilesK = K >> 5;
  const int nt = tilesK * (N >> 5);
  if ((int)blockIdx.x >= nt) return;
  const int tk = blockIdx.x % tilesK, tn = blockIdx.x / tilesK;
  const int k0 = tk * 32, n0 = tn * 32;
  const int t = threadIdx.x;
  const int r = t >> 3, c4 = (t & 7) * 4;
  float4 v = make_float4(0.f, 0.f, 0.f, 0.f);
  if (src) v = *(const float4*)(src + (size_t)(k0 + r) * N + n0 + c4);
  tile[r][c4] = v.x; tile[r][c4 + 1] = v.y; tile[r][c4 + 2] = v.z; tile[r][c4 + 3] = v.w;
  __syncthreads();
  const int nn = t >> 3, kc = (t & 7) * 4;
  s16x4 o;
  o.x = f2b(tile[kc][nn]); o.y = f2b(tile[kc + 1][nn]);
  o.z = f2b(tile[kc + 2][nn]); o.w = f2b(tile[kc + 3][nn]);
  *(s16x4*)(dst + (size_t)(noff + n0 + nn) * K + k0 + kc) = o;
}

// ---------------------------------------------------------------------------
// value fp32 [12600x256] -> bf16 [12672x256] (zero-padded rows)
// ---------------------------------------------------------------------------
__global__ __launch_bounds__(256) void vconvert(const float* __restrict__ x,
                                                short* __restrict__ y)
{
  const int i = (blockIdx.x * 256 + threadIdx.x) * 4;
  if (i >= 12672 * 256) return;
  s16x4 o = (s16x4){0, 0, 0, 0};
  if (i < 12600 * 256) {
    float4 v = *(const float4*)(x + i);
    o.x = f2b(v.x); o.y = f2b(v.y); o.z = f2b(v.z); o.w = f2b(v.w);
  }
  *(s16x4*)(y + i) = o;
}

// ---------------------------------------------------------------------------
// LayerNorm: one wave per row of 256. Outputs bf16: yb (normalized),
// ybp (normalized + pos, only if pos != null).
// ---------------------------------------------------------------------------
__global__ __launch_bounds__(256) void ln_kernel(
    const float* __restrict__ x, const float* __restrict__ pos,
    const float* __restrict__ g, const float* __restrict__ bta,
    short* __restrict__ yb, short* __restrict__ ybp)
{
  const int row  = blockIdx.x * 4 + (threadIdx.x >> 6);
  const int lane = threadIdx.x & 63;
  const float4 v = ((const float4*)(x + (size_t)row * 256))[lane];
  float s = v.x + v.y + v.z + v.w;
#pragma unroll
  for (int o = 32; o; o >>= 1) s += __shfl_xor(s, o);
  const float mean = s * (1.f / 256.f);
  const float dx = v.x - mean, dy = v.y - mean, dz = v.z - mean, dw = v.w - mean;
  float s2 = dx * dx + dy * dy + dz * dz + dw * dw;
#pragma unroll
  for (int o = 32; o; o >>= 1) s2 += __shfl_xor(s2, o);
  const float inv = rsqrtf(s2 * (1.f / 256.f) + 1e-5f);
  const float4 gv = ((const float4*)g)[lane];
  const float4 bv = ((const float4*)bta)[lane];
  const float4 o1 = make_float4(dx * inv * gv.x + bv.x, dy * inv * gv.y + bv.y,
                                dz * inv * gv.z + bv.z, dw * inv * gv.w + bv.w);
  if (yb) {
    s16x4 ob; ob.x = f2b(o1.x); ob.y = f2b(o1.y); ob.z = f2b(o1.z); ob.w = f2b(o1.w);
    ((s16x4*)(yb + (size_t)row * 256))[lane] = ob;
  }
  if (pos && ybp) {
    const float4 pv = ((const float4*)(pos + (size_t)row * 256))[lane];
    s16x4 ob;
    ob.x = f2b(o1.x + pv.x); ob.y = f2b(o1.y + pv.y);
    ob.z = f2b(o1.z + pv.z); ob.w = f2b(o1.w + pv.w);
    ((s16x4*)(ybp + (size_t)row * 256))[lane] = ob;
  }
}

// ---------------------------------------------------------------------------
// bf16 MFMA GEMM: 128x128 tile, BK=64. B staged via global_load_lds into
// 16 KB LDS (8-chunk rotation swizzle, conflict-free); A-fragments loaded
// per-lane directly from global (short8, L2/L3-resident, no barrier dep).
// Operand-swapped MFMA; LDS-staged coalesced epilogue (16-row bands).
// EPI: 1=gelu->bf16 | 2=f32: bias + b2f(bf16 add1) + f32 add2
//      3=f32: bias + f32 add1 | 4=oa (bias split 192/96, f32) | 5=bf16+bias
// ---------------------------------------------------------------------------
template <int EPI>
__global__ __launch_bounds__(256) void gemm_bf16(
    const short* __restrict__ A, const short* __restrict__ Bt,
    const float* __restrict__ bias, const float* __restrict__ bias2,
    const void* __restrict__ add1, const float* __restrict__ add2,
    void* __restrict__ Cout, int M, int Nreal, int ldc, int K)
{
  __shared__ __align__(16) char smem[16384];
  short* sB = (short*)smem;       // [128][64] shorts, pos-swizzled
  float* sf = (float*)smem;       // epilogue staging [16][132]

  const int t = threadIdx.x;
  const int wave = t >> 6, lane = t & 63;
  const int quad = lane >> 4, l16 = lane & 15;
  const int wm = (wave & 1) * 64, wn = (wave >> 1) * 64;
  const int m0 = blockIdx.y * 128, n0 = blockIdx.x * 128;

  f32x4 acc[4][4];
#pragma unroll
  for (int i = 0; i < 4; i++)
#pragma unroll
    for (int j = 0; j < 4; j++) acc[i][j] = (f32x4){0.f, 0.f, 0.f, 0.f};

  // B staging: lane L: srow=L>>3 (8 rows/glds), pos=L&7; stages global
  // k-chunk (pos+srow)&7 at LDS position pos (glds dest = base + L*16B).
  const int srow = lane >> 3, pos = lane & 7;
  const int chunk = (pos + srow) & 7;
  const short* gB = Bt + (size_t)(n0 + wave * 32 + srow) * K + chunk * 8;
  // A: per-lane direct global fragment base (row = m0+wm+i*16+l16)
  const short* gA = A + (size_t)(m0 + wm + l16) * K + quad * 8;

  const int nk = K >> 6;
  for (int kt = 0; kt < nk; ++kt) {
    if (kt) __syncthreads();
    const int ko = kt * 64;
#pragma unroll
    for (int g = 0; g < 4; ++g)
      glds16(gB + ko + (size_t)(g * 8) * K, sB + (wave * 32 + g * 8) * 64);
    __syncthreads();
#pragma unroll
    for (int kk = 0; kk < 2; ++kk) {
      const int c = kk * 4 + quad;
      short8 af[4], bf[4];
      const short* pa = gA + ko + kk * 32;
#pragma unroll
      for (int i = 0; i < 4; i++)
        af[i] = *(const short8*)(pa + (size_t)(i * 16) * K);
#pragma unroll
      for (int j = 0; j < 4; j++) {
        const int lr = wn + j * 16 + l16;
        bf[j] = *(const short8*)&sB[lr * 64 + ((c - lr) & 7) * 8];
      }
      // SWAPPED operands: l16 -> C row, quad*4+r -> C col
#pragma unroll
      for (int i = 0; i < 4; i++)
#pragma unroll
        for (int j = 0; j < 4; j++) acc[i][j] = mfma16(bf[j], af[i], acc[i][j]);
    }
  }
  __syncthreads();

  // Epilogue: 8 bands of 16 rows x 128 cols staged in LDS, stored with
  // consecutive-lane addresses (full cachelines).
#pragma unroll
  for (int b = 0; b < 8; ++b) {
    if ((wave & 1) == (b >> 2)) {
      const int i = b & 3;
#pragma unroll
      for (int j = 0; j < 4; ++j)
        *(f32x4*)&sf[l16 * 132 + wn + quad * 4 + j * 16] = acc[i][j];
    }
    __syncthreads();
#pragma unroll
    for (int r2 = 0; r2 < 2; ++r2) {
      const int fidx = r2 * 1024 + t * 4;
      const int row = fidx >> 7, col = fidx & 127;
      const int gm = m0 + b * 16 + row;
      const int cc = n0 + col;
      if (gm < M && cc < Nreal) {
        const float4 v = *(const float4*)&sf[row * 132 + col];
        float4 bb;
        if (EPI == 4) bb = (cc < 192) ? *(const float4*)(bias + cc)
                                      : *(const float4*)(bias2 + cc - 192);
        else bb = *(const float4*)(bias + cc);
        float v0 = v.x + bb.x, v1 = v.y + bb.y, v2 = v.z + bb.z, v3 = v.w + bb.w;
        if (EPI == 1) {
          v0 = gelu1(v0); v1 = gelu1(v1); v2 = gelu1(v2); v3 = gelu1(v3);
          s16x4 o; o.x = f2b(v0); o.y = f2b(v1); o.z = f2b(v2); o.w = f2b(v3);
          *(s16x4*)((short*)Cout + (size_t)gm * ldc + cc) = o;
        } else if (EPI == 5) {
          s16x4 o; o.x = f2b(v0); o.y = f2b(v1); o.z = f2b(v2); o.w = f2b(v3);
          *(s16x4*)((short*)Cout + (size_t)gm * ldc + cc) = o;
        } else {
          if (EPI == 2) {
            const s16x4 a1 = *(const s16x4*)((const short*)add1 + (size_t)gm * ldc + cc);
            v0 += b2f(a1.x); v1 += b2f(a1.y); v2 += b2f(a1.z); v3 += b2f(a1.w);
            const float4 a2 = *(const float4*)(add2 + (size_t)gm * ldc + cc);
            v0 += a2.x; v1 += a2.y; v2 += a2.z; v3 += a2.w;
          } else if (EPI == 3) {
            const float4 a1 = *(const float4*)((const float*)add1 + (size_t)gm * ldc + cc);
            v0 += a1.x; v1 += a1.y; v2 += a1.z; v3 += a1.w;
          }
          *(float4*)((float*)Cout + (size_t)gm * ldc + cc) =
              make_float4(v0, v1, v2, v3);
        }
      }
    }
    __syncthreads();
  }
}

// ---------------------------------------------------------------------------
// prep_points: one thread per (row, head). Fused softmax + bilinear setup.
// ---------------------------------------------------------------------------
__global__ __launch_bounds__(256) void prep_points(
    const float* __restrict__ oa, const float* __restrict__ refp,
    int4* __restrict__ tIdx, s16x4* __restrict__ tW)
{
  const int t = blockIdx.x * 256 + threadIdx.x;   // 131072 = 16384*8
  const int row = t >> 3, h = t & 7;
  const float* oarow = oa + (size_t)row * 288;

  float off[24];
  const float4* op = (const float4*)(oarow + h * 24);
#pragma unroll
  for (int i = 0; i < 6; i++) {
    const float4 v = op[i];
    off[i * 4] = v.x; off[i * 4 + 1] = v.y; off[i * 4 + 2] = v.z; off[i * 4 + 3] = v.w;
  }
  float lg[12];
  const float4* ap = (const float4*)(oarow + 192 + h * 12);
#pragma unroll
  for (int i = 0; i < 3; i++) {
    const float4 v = ap[i];
    lg[i * 4] = v.x; lg[i * 4 + 1] = v.y; lg[i * 4 + 2] = v.z; lg[i * 4 + 3] = v.w;
  }
  const float* rp = refp + (size_t)row * 6;
  const float Rx[3] = {rp[0], rp[2], rp[4]}, Ry[3] = {rp[1], rp[3], rp[5]};

  float mx = lg[0];
#pragma unroll
  for (int i = 1; i < 12; i++) mx = fmaxf(mx, lg[i]);
  float sum = 0.f;
#pragma unroll
  for (int i = 0; i < 12; i++) { lg[i] = __expf(lg[i] - mx); sum += lg[i]; }
  const float inv = 1.f / sum;

  const int b = row >> 13;
  const int Hs[3] = {60, 30, 15}, Ws[3] = {80, 40, 20}, St[3] = {0, 4800, 6000};

  int4* ti = tIdx + (size_t)t * 12;
  s16x4* tw = tW + (size_t)t * 12;
#pragma unroll
  for (int p = 0; p < 12; p++) {
    const int l = p >> 2;
    const int W = Ws[l], H = Hs[l];
    const float gx = Rx[l] * W + off[p * 2]     - 0.5f;
    const float gy = Ry[l] * H + off[p * 2 + 1] - 0.5f;
    const float x0f = floorf(gx), y0f = floorf(gy);
    const float wx = gx - x0f, wy = gy - y0f;
    const int x0 = (int)x0f, y0 = (int)y0f;
    const float aw = lg[p] * inv;
    float cw[4] = {(1.f - wx) * (1.f - wy), wx * (1.f - wy),
                   (1.f - wx) * wy, wx * wy};
    const int base = b * 6300 + St[l];
    int ci[4];
#pragma unroll
    for (int k = 0; k < 4; k++) {
      const int xx = x0 + (k & 1), yy = y0 + (k >> 1);
      const bool valid = (xx >= 0) & (xx < W) & (yy >= 0) & (yy < H);
      const int xc = min(max(xx, 0), W - 1);
      const int yc = min(max(yy, 0), H - 1);
      ci[k] = ((base + yc * W + xc) << 8) + h * 32;
      cw[k] = valid ? cw[k] * aw : 0.f;
    }
    ti[p] = make_int4(ci[0], ci[1], ci[2], ci[3]);
    s16x4 wv; wv.x = f2b(cw[0]); wv.y = f2b(cw[1]); wv.z = f2b(cw[2]); wv.w = f2b(cw[3]);
    tw[p] = wv;
  }
}

// ---------------------------------------------------------------------------
// deform_gather: thread = (row, h, c4); c4 covers 8 channels via 16 B loads.
// ---------------------------------------------------------------------------
__global__ __launch_bounds__(256) void deform_gather(
    const short* __restrict__ vproj, const int4* __restrict__ tIdx,
    const s16x4* __restrict__ tW, short* __restrict__ out)
{
  const int t = blockIdx.x * 256 + threadIdx.x;  // 524288 = 16384*8*4
  const int unit = t >> 2, c4 = (t & 3) * 8;
  const int4* ip = tIdx + (size_t)unit * 12;
  const s16x4* wp = tW + (size_t)unit * 12;
  float acc[8];
#pragma unroll
  for (int i = 0; i < 8; i++) acc[i] = 0.f;

#pragma unroll 2
  for (int p = 0; p < 12; p++) {
    const int4 idx = ip[p];
    const s16x4 wb = wp[p];
    const float w0 = b2f(wb.x), w1 = b2f(wb.y), w2 = b2f(wb.z), w3 = b2f(wb.w);
    const short8 v0 = *(const short8*)(vproj + idx.x + c4);
    const short8 v1 = *(const short8*)(vproj + idx.y + c4);
    const short8 v2 = *(const short8*)(vproj + idx.z + c4);
    const short8 v3 = *(const short8*)(vproj + idx.w + c4);
    float f0[8], f1[8], f2[8], f3[8];
    b8f(v0, f0); b8f(v1, f1); b8f(v2, f2); b8f(v3, f3);
#pragma unroll
    for (int j = 0; j < 8; j++)
      acc[j] += w0 * f0[j] + w1 * f1[j] + w2 * f2[j] + w3 * f3[j];
  }
  short8 o;
#pragma unroll
  for (int j = 0; j < 8; j++) o[j] = f2b(acc[j]);
  *(short8*)(out + (size_t)t * 8) = o;
}

// ---------------------------------------------------------------------------
// Launch
// ---------------------------------------------------------------------------
extern "C" void kernel_launch(void* const* d_in, const int* in_sizes, int n_in,
                              void* d_out, int out_size, void* d_ws, size_t ws_size,
                              hipStream_t stream)
{
  const float* query     = (const float*)d_in[0];
  const float* value     = (const float*)d_in[1];
  const float* query_pos = (const float*)d_in[2];
  const float* ref_pts   = (const float*)d_in[3];
  const float* g1  = (const float*)d_in[6];
  const float* b1  = (const float*)d_in[7];
  const float* Wo  = (const float*)d_in[8];
  const float* bo  = (const float*)d_in[9];
  const float* Wa  = (const float*)d_in[10];
  const float* ba  = (const float*)d_in[11];
  const float* Wv  = (const float*)d_in[12];
  const float* bv  = (const float*)d_in[13];
  const float* Wp  = (const float*)d_in[14];
  const float* bp  = (const float*)d_in[15];
  const float* g2  = (const float*)d_in[16];
  const float* b2  = (const float*)d_in[17];
  const float* Wf1 = (const float*)d_in[18];
  const float* bf1 = (const float*)d_in[19];
  const float* Wf2 = (const float*)d_in[20];
  const float* bf2 = (const float*)d_in[21];

  char* ws = (char*)d_ws;
  short* wt_oa   = (short*)(ws + 0);          // 384x256 bf16
  short* wt_v    = (short*)(ws + 196608);
  short* wt_p    = (short*)(ws + 327680);
  short* wt_f1   = (short*)(ws + 458752);
  short* wt_f2   = (short*)(ws + 983040);
  short* qnb     = (short*)(ws + 1507328);    // 16384x256 bf16 (LN1, no pos)
  short* qa      = (short*)(ws + 18284544);   // 16384x256 bf16 (later q2)
  float* oabuf   = (float*)(ws + 26673152);   // 16384x288 f32 (dead after prep)
  short* vproj   = (short*)(ws + 45547520);   // 12600x256 bf16
  short* sampled = (short*)(ws + 51998720);   // 16384x256 bf16
  float* qbuf    = (float*)(ws + 60387328);   // 16384x256 f32 (after tables die)
  short* valbf   = (short*)(ws + 77164544);   // 12672x256 bf16
  int4*  tIdx    = (int4*)(ws + 60387328);    // overlaps qbuf+valbf
  s16x4* tW      = (s16x4*)(ws + 85553152);   // end 98,136,064
  short* q2      = qa;
  short* hidden  = (short*)(ws + 26673152);   // 16384x1024 bf16 (ends 60,227,584)
  float* outp = (float*)d_out;

  wconvert<<<dim3(256, 7), 256, 0, stream>>>(Wo, Wa, Wv, Wp, Wf1, Wf2,
                                             wt_oa, wt_v, wt_p, wt_f1, wt_f2);
  vconvert<<<3169, 256, 0, stream>>>(value, valbf);
  // LN1: qnb = LN(query) bf16; qa = (LN(query)+pos) bf16
  ln_kernel<<<4096, 256, 0, stream>>>(query, query_pos, g1, b1, qnb, qa);
  // oa = qa @ [Wo|Wa] + [bo|ba]   [16384 x 288] f32 (raw logits)
  gemm_bf16<4><<<dim3(3, 128), 256, 0, stream>>>(qa, wt_oa, bo, ba, nullptr,
                                                 nullptr, oabuf, 16384, 288, 288, 256);
  // vproj = value @ Wv + bv -> bf16   [12600 x 256]
  gemm_bf16<5><<<dim3(2, 99), 256, 0, stream>>>(valbf, wt_v, bv, nullptr, nullptr,
                                                nullptr, vproj, 12600, 256, 256, 256);
  prep_points<<<512, 256, 0, stream>>>(oabuf, ref_pts, tIdx, tW);
  deform_gather<<<2048, 256, 0, stream>>>(vproj, tIdx, tW, sampled);
  // qbuf = sampled @ Wp + bp + b2f(qnb) + query   f32
  gemm_bf16<2><<<dim3(2, 128), 256, 0, stream>>>(sampled, wt_p, bp, nullptr, qnb,
                                                 query, qbuf, 16384, 256, 256, 256);
  // LN2: q2 = LN(qbuf) bf16
  ln_kernel<<<4096, 256, 0, stream>>>(qbuf, nullptr, g2, b2, q2, nullptr);
  // hidden = gelu(q2 @ Wf1 + bf1) bf16   [16384 x 1024]
  gemm_bf16<1><<<dim3(8, 128), 256, 0, stream>>>(q2, wt_f1, bf1, nullptr, nullptr,
                                                 nullptr, hidden, 16384, 1024, 1024, 256);
  // out = qbuf + hidden @ Wf2 + bf2   f32
  gemm_bf16<3><<<dim3(2, 128), 256, 0, stream>>>(hidden, wt_f2, bf2, nullptr, qbuf,
                                                 nullptr, outp, 16384, 256, 256, 1024);
}

// Round 8
// 238.988 us; speedup vs baseline: 1.3456x; 1.3456x over previous
//
#include <hip/hip_runtime.h>
#include <math.h>

// ---------------------------------------------------------------------------
// Deformable transformer layer, MI355X round-8:
//  - GEMM core: exact round-6 structure (A+B staged via global_load_lds,
//    128x128 tile, BK=64, 32KB LDS, 8-chunk rotation swizzle, swapped MFMA,
//    LDS-staged coalesced epilogue). Refactored to a device core.
//  - Merged launches: prep_all (wconvert+vconvert+LN1), gemm_oa_v (two
//    GEMMs in one grid), deform_fused (prep tables in LDS + gather).
//  7 dispatches total.
// B=2, Nq=8192, C=256, HEADS=8, dh=32, LEVELS=3, POINTS=4, MLP=4
// ---------------------------------------------------------------------------

typedef short short8 __attribute__((ext_vector_type(8)));
typedef short s16x4 __attribute__((ext_vector_type(4)));
typedef __bf16 bf16x8 __attribute__((ext_vector_type(8)));
typedef float f32x4 __attribute__((ext_vector_type(4)));

__device__ __forceinline__ short f2b(float f) {
  unsigned u = __builtin_bit_cast(unsigned, f);
  u += 0x7fffu + ((u >> 16) & 1u);   // RNE to bf16
  return (short)(u >> 16);
}
__device__ __forceinline__ float b2f(short s) {
  unsigned u = ((unsigned)(unsigned short)s) << 16;
  return __builtin_bit_cast(float, u);
}
__device__ __forceinline__ void b8f(short8 s, float* f) {
  const uint4 u = __builtin_bit_cast(uint4, s);
  f[0] = __builtin_bit_cast(float, u.x << 16);
  f[1] = __builtin_bit_cast(float, u.x & 0xffff0000u);
  f[2] = __builtin_bit_cast(float, u.y << 16);
  f[3] = __builtin_bit_cast(float, u.y & 0xffff0000u);
  f[4] = __builtin_bit_cast(float, u.z << 16);
  f[5] = __builtin_bit_cast(float, u.z & 0xffff0000u);
  f[6] = __builtin_bit_cast(float, u.w << 16);
  f[7] = __builtin_bit_cast(float, u.w & 0xffff0000u);
}

__device__ __forceinline__ f32x4 mfma16(short8 a, short8 b, f32x4 c) {
  return __builtin_amdgcn_mfma_f32_16x16x32_bf16(
      __builtin_bit_cast(bf16x8, a), __builtin_bit_cast(bf16x8, b), c, 0, 0, 0);
}

typedef __attribute__((address_space(3))) unsigned int lds_u32;
typedef const __attribute__((address_space(1))) unsigned int glb_u32;
__device__ __forceinline__ void glds16(const void* g, void* l) {
  __builtin_amdgcn_global_load_lds((glb_u32*)g, (lds_u32*)l, 16, 0, 0);
}

__device__ __forceinline__ float gelu1(float v) {
  return 0.5f * v * (1.f + erff(v * 0.70710678118654752f));
}

// ---------------------------------------------------------------------------
// GEMM core (round-6 structure). smem must be 32 KB, 16-B aligned.
// EPI: 1=gelu->bf16 | 2=f32: bias + b2f(bf16 add1) + f32 add2
//      3=f32: bias + f32 add1 | 4=oa (bias split 192/96, f32) | 5=bf16+bias
// ---------------------------------------------------------------------------
template <int EPI>
__device__ __forceinline__ void gemm_core(
    int bx, int by,
    const short* __restrict__ A, const short* __restrict__ Bt,
    const float* __restrict__ bias, const float* __restrict__ bias2,
    const void* __restrict__ add1, const float* __restrict__ add2,
    void* __restrict__ Cout, int M, int Nreal, int ldc, int K, char* smem)
{
  short* sA = (short*)smem;       // [128][64] shorts, pos-swizzled
  short* sB = sA + 8192;          // [128][64]
  float* sf = (float*)smem;       // epilogue staging [32][132]

  const int t = threadIdx.x;
  const int wave = t >> 6, lane = t & 63;
  const int quad = lane >> 4, l16 = lane & 15;
  const int wm = (wave & 1) * 64, wn = (wave >> 1) * 64;
  const int m0 = by * 128, n0 = bx * 128;

  f32x4 acc[4][4];
#pragma unroll
  for (int i = 0; i < 4; i++)
#pragma unroll
    for (int j = 0; j < 4; j++) acc[i][j] = (f32x4){0.f, 0.f, 0.f, 0.f};

  // Staging: lane L: srow=L>>3, pos=L&7; stages global k-chunk (pos+srow)&7
  // at LDS position pos of row srow (glds dest = base + L*16B).
  const int srow = lane >> 3, pos = lane & 7;
  const int chunk = (pos + srow) & 7;
  const short* gA = A + (size_t)(m0 + wave * 32 + srow) * K + chunk * 8;
  const short* gB = Bt + (size_t)(n0 + wave * 32 + srow) * K + chunk * 8;

  const int nk = K >> 6;
  for (int kt = 0; kt < nk; ++kt) {
    if (kt) __syncthreads();
    const int ko = kt * 64;
#pragma unroll
    for (int g = 0; g < 4; ++g) {
      glds16(gA + ko + (size_t)(g * 8) * K, sA + (wave * 32 + g * 8) * 64);
      glds16(gB + ko + (size_t)(g * 8) * K, sB + (wave * 32 + g * 8) * 64);
    }
    __syncthreads();
#pragma unroll
    for (int kk = 0; kk < 2; ++kk) {
      short8 af[4], bf[4];
      const int c = kk * 4 + quad;
#pragma unroll
      for (int i = 0; i < 4; i++) {
        const int lrA = wm + i * 16 + l16;
        af[i] = *(const short8*)&sA[lrA * 64 + ((c - lrA) & 7) * 8];
        const int lrB = wn + i * 16 + l16;
        bf[i] = *(const short8*)&sB[lrB * 64 + ((c - lrB) & 7) * 8];
      }
      // SWAPPED operands: l16 -> C row, quad*4+r -> C col
#pragma unroll
      for (int i = 0; i < 4; i++)
#pragma unroll
        for (int j = 0; j < 4; j++) acc[i][j] = mfma16(bf[j], af[i], acc[i][j]);
    }
  }
  __syncthreads();

  // Epilogue: 4 bands of 32 rows x 128 cols staged in LDS, stored with
  // consecutive-lane addresses (full cachelines).
#pragma unroll
  for (int b = 0; b < 4; ++b) {
    const bool mine = (b < 2) ? (wm == 0) : (wm == 64);
    if (mine) {
#pragma unroll
      for (int ii = 0; ii < 2; ++ii) {
        const int i = (b & 1) * 2 + ii;
        const int rr = ii * 16 + l16;
#pragma unroll
        for (int j = 0; j < 4; ++j)
          *(f32x4*)&sf[rr * 132 + wn + quad * 4 + j * 16] = acc[i][j];
      }
    }
    __syncthreads();
#pragma unroll
    for (int r2 = 0; r2 < 4; ++r2) {
      const int fidx = r2 * 1024 + t * 4;
      const int row = fidx >> 7, col = fidx & 127;
      const int gm = m0 + b * 32 + row;
      const int cc = n0 + col;
      if (gm < M && cc < Nreal) {
        const float4 v = *(const float4*)&sf[row * 132 + col];
        float4 bb;
        if (EPI == 4) bb = (cc < 192) ? *(const float4*)(bias + cc)
                                      : *(const float4*)(bias2 + cc - 192);
        else bb = *(const float4*)(bias + cc);
        float v0 = v.x + bb.x, v1 = v.y + bb.y, v2 = v.z + bb.z, v3 = v.w + bb.w;
        if (EPI == 1) {
          v0 = gelu1(v0); v1 = gelu1(v1); v2 = gelu1(v2); v3 = gelu1(v3);
          s16x4 o; o.x = f2b(v0); o.y = f2b(v1); o.z = f2b(v2); o.w = f2b(v3);
          *(s16x4*)((short*)Cout + (size_t)gm * ldc + cc) = o;
        } else if (EPI == 5) {
          s16x4 o; o.x = f2b(v0); o.y = f2b(v1); o.z = f2b(v2); o.w = f2b(v3);
          *(s16x4*)((short*)Cout + (size_t)gm * ldc + cc) = o;
        } else {
          if (EPI == 2) {
            const s16x4 a1 = *(const s16x4*)((const short*)add1 + (size_t)gm * ldc + cc);
            v0 += b2f(a1.x); v1 += b2f(a1.y); v2 += b2f(a1.z); v3 += b2f(a1.w);
            const float4 a2 = *(const float4*)(add2 + (size_t)gm * ldc + cc);
            v0 += a2.x; v1 += a2.y; v2 += a2.z; v3 += a2.w;
          } else if (EPI == 3) {
            const float4 a1 = *(const float4*)((const float*)add1 + (size_t)gm * ldc + cc);
            v0 += a1.x; v1 += a1.y; v2 += a1.z; v3 += a1.w;
          }
          *(float4*)((float*)Cout + (size_t)gm * ldc + cc) =
              make_float4(v0, v1, v2, v3);
        }
      }
    }
    __syncthreads();
  }
}

template <int EPI>
__global__ __launch_bounds__(256) void gemm_k(
    const short* __restrict__ A, const short* __restrict__ Bt,
    const float* __restrict__ bias, const float* __restrict__ bias2,
    const void* __restrict__ add1, const float* __restrict__ add2,
    void* __restrict__ Cout, int M, int Nreal, int ldc, int K)
{
  __shared__ __align__(16) char smem[32768];
  gemm_core<EPI>(blockIdx.x, blockIdx.y, A, Bt, bias, bias2, add1, add2,
                 Cout, M, Nreal, ldc, K, smem);
}

// Merged: blocks [0,384) -> oa GEMM (EPI4, 3x128), [384,582) -> v GEMM (EPI5, 2x99)
__global__ __launch_bounds__(256) void gemm_oa_v(
    const short* __restrict__ qa, const short* __restrict__ wt_oa,
    const float* __restrict__ bo, const float* __restrict__ ba,
    float* __restrict__ oabuf,
    const short* __restrict__ valbf, const short* __restrict__ wt_v,
    const float* __restrict__ bv, short* __restrict__ vproj)
{
  __shared__ __align__(16) char smem[32768];
  const int idx = blockIdx.x;
  if (idx < 384) {
    gemm_core<4>(idx % 3, idx / 3, qa, wt_oa, bo, ba, nullptr, nullptr,
                 oabuf, 16384, 288, 288, 256, smem);
  } else {
    const int r = idx - 384;
    gemm_core<5>(r % 2, r / 2, valbf, wt_v, bv, nullptr, nullptr, nullptr,
                 vproj, 12600, 256, 256, 256, smem);
  }
}

// ---------------------------------------------------------------------------
// prep_all: merged wconvert (1792 blocks) + vconvert (3169) + LN1 (4096).
// ---------------------------------------------------------------------------
__global__ __launch_bounds__(256) void prep_all(
    const float* __restrict__ Wo, const float* __restrict__ Wa,
    const float* __restrict__ Wv, const float* __restrict__ Wp,
    const float* __restrict__ Wf1, const float* __restrict__ Wf2,
    short* __restrict__ t_oa, short* __restrict__ t_v, short* __restrict__ t_p,
    short* __restrict__ t_f1, short* __restrict__ t_f2,
    const float* __restrict__ value, short* __restrict__ valbf,
    const float* __restrict__ query, const float* __restrict__ query_pos,
    const float* __restrict__ g1, const float* __restrict__ b1,
    short* __restrict__ qnb, short* __restrict__ qa)
{
  __shared__ float tile[32][33];
  const int t = threadIdx.x;
  const int blk = blockIdx.x;

  if (blk < 1792) {
    // ---- wconvert: Wt[n][k] bf16 from W[k][n] fp32 ----
    const int bxa = blk & 255, bya = blk >> 8;
    int K, N, noff; const float* src; short* dst;
    switch (bya) {
      case 0: src = Wo;      dst = t_oa; K = 256;  N = 192;  noff = 0;   break;
      case 1: src = Wa;      dst = t_oa; K = 256;  N = 96;   noff = 192; break;
      case 2: src = nullptr; dst = t_oa; K = 256;  N = 96;   noff = 288; break;
      case 3: src = Wv;      dst = t_v;  K = 256;  N = 256;  noff = 0;   break;
      case 4: src = Wp;      dst = t_p;  K = 256;  N = 256;  noff = 0;   break;
      case 5: src = Wf1;     dst = t_f1; K = 256;  N = 1024; noff = 0;   break;
      default: src = Wf2;    dst = t_f2; K = 1024; N = 256;  noff = 0;   break;
    }
    const int tilesK = K >> 5;
    const int nt = tilesK * (N >> 5);
    if (bxa >= nt) return;
    const int tk = bxa % tilesK, tn = bxa / tilesK;
    const int k0 = tk * 32, n0 = tn * 32;
    const int r = t >> 3, c4 = (t & 7) * 4;
    float4 v = make_float4(0.f, 0.f, 0.f, 0.f);
    if (src) v = *(const float4*)(src + (size_t)(k0 + r) * N + n0 + c4);
    tile[r][c4] = v.x; tile[r][c4 + 1] = v.y; tile[r][c4 + 2] = v.z; tile[r][c4 + 3] = v.w;
    __syncthreads();
    const int nn = t >> 3, kc = (t & 7) * 4;
    s16x4 o;
    o.x = f2b(tile[kc][nn]); o.y = f2b(tile[kc + 1][nn]);
    o.z = f2b(tile[kc + 2][nn]); o.w = f2b(tile[kc + 3][nn]);
    *(s16x4*)(dst + (size_t)(noff + n0 + nn) * K + k0 + kc) = o;
  } else if (blk < 1792 + 3169) {
    // ---- vconvert: value fp32 -> bf16 [12672x256] zero-padded ----
    const int i = ((blk - 1792) * 256 + t) * 4;
    if (i >= 12672 * 256) return;
    s16x4 o = (s16x4){0, 0, 0, 0};
    if (i < 12600 * 256) {
      float4 v = *(const float4*)(value + i);
      o.x = f2b(v.x); o.y = f2b(v.y); o.z = f2b(v.z); o.w = f2b(v.w);
    }
    *(s16x4*)(valbf + i) = o;
  } else {
    // ---- LN1: qnb = LN(query) bf16; qa = (LN(query)+pos) bf16 ----
    const int row  = (blk - 4961) * 4 + (t >> 6);
    const int lane = t & 63;
    const float4 v = ((const float4*)(query + (size_t)row * 256))[lane];
    float s = v.x + v.y + v.z + v.w;
#pragma unroll
    for (int o = 32; o; o >>= 1) s += __shfl_xor(s, o);
    const float mean = s * (1.f / 256.f);
    const float dx = v.x - mean, dy = v.y - mean, dz = v.z - mean, dw = v.w - mean;
    float s2 = dx * dx + dy * dy + dz * dz + dw * dw;
#pragma unroll
    for (int o = 32; o; o >>= 1) s2 += __shfl_xor(s2, o);
    const float inv = rsqrtf(s2 * (1.f / 256.f) + 1e-5f);
    const float4 gv = ((const float4*)g1)[lane];
    const float4 bv = ((const float4*)b1)[lane];
    const float4 o1 = make_float4(dx * inv * gv.x + bv.x, dy * inv * gv.y + bv.y,
                                  dz * inv * gv.z + bv.z, dw * inv * gv.w + bv.w);
    s16x4 ob; ob.x = f2b(o1.x); ob.y = f2b(o1.y); ob.z = f2b(o1.z); ob.w = f2b(o1.w);
    ((s16x4*)(qnb + (size_t)row * 256))[lane] = ob;
    const float4 pv = ((const float4*)(query_pos + (size_t)row * 256))[lane];
    s16x4 op;
    op.x = f2b(o1.x + pv.x); op.y = f2b(o1.y + pv.y);
    op.z = f2b(o1.z + pv.z); op.w = f2b(o1.w + pv.w);
    ((s16x4*)(qa + (size_t)row * 256))[lane] = op;
  }
}

// ---------------------------------------------------------------------------
// LayerNorm (standalone, for LN2): one wave per row; bf16 out.
// ---------------------------------------------------------------------------
__global__ __launch_bounds__(256) void ln_kernel(
    const float* __restrict__ x, const float* __restrict__ g,
    const float* __restrict__ bta, short* __restrict__ yb)
{
  const int row  = blockIdx.x * 4 + (threadIdx.x >> 6);
  const int lane = threadIdx.x & 63;
  const float4 v = ((const float4*)(x + (size_t)row * 256))[lane];
  float s = v.x + v.y + v.z + v.w;
#pragma unroll
  for (int o = 32; o; o >>= 1) s += __shfl_xor(s, o);
  const float mean = s * (1.f / 256.f);
  const float dx = v.x - mean, dy = v.y - mean, dz = v.z - mean, dw = v.w - mean;
  float s2 = dx * dx + dy * dy + dz * dz + dw * dw;
#pragma unroll
  for (int o = 32; o; o >>= 1) s2 += __shfl_xor(s2, o);
  const float inv = rsqrtf(s2 * (1.f / 256.f) + 1e-5f);
  const float4 gv = ((const float4*)g)[lane];
  const float4 bv = ((const float4*)bta)[lane];
  s16x4 ob;
  ob.x = f2b(dx * inv * gv.x + bv.x); ob.y = f2b(dy * inv * gv.y + bv.y);
  ob.z = f2b(dz * inv * gv.z + bv.z); ob.w = f2b(dw * inv * gv.w + bv.w);
  ((s16x4*)(yb + (size_t)row * 256))[lane] = ob;
}

// ---------------------------------------------------------------------------
// deform_fused: block = 8 rows. Phase 1 (64 threads): softmax + bilinear
// setup -> LDS tables. Phase 2 (256 threads): pure gather+FMA.
// ---------------------------------------------------------------------------
__global__ __launch_bounds__(256) void deform_fused(
    const short* __restrict__ vproj, const float* __restrict__ oa,
    const float* __restrict__ refp, short* __restrict__ out)
{
  __shared__ int4 sIdx[768];   // [64 units][12 points]
  __shared__ s16x4 sW[768];
  const int t = threadIdx.x;

  if (t < 64) {
    const int row = blockIdx.x * 8 + (t >> 3), h = t & 7;
    const float* oarow = oa + (size_t)row * 288;
    float off[24];
    const float4* op = (const float4*)(oarow + h * 24);
#pragma unroll
    for (int i = 0; i < 6; i++) {
      const float4 v = op[i];
      off[i * 4] = v.x; off[i * 4 + 1] = v.y; off[i * 4 + 2] = v.z; off[i * 4 + 3] = v.w;
    }
    float lg[12];
    const float4* ap = (const float4*)(oarow + 192 + h * 12);
#pragma unroll
    for (int i = 0; i < 3; i++) {
      const float4 v = ap[i];
      lg[i * 4] = v.x; lg[i * 4 + 1] = v.y; lg[i * 4 + 2] = v.z; lg[i * 4 + 3] = v.w;
    }
    const float* rp = refp + (size_t)row * 6;
    const float Rx[3] = {rp[0], rp[2], rp[4]}, Ry[3] = {rp[1], rp[3], rp[5]};
    float mx = lg[0];
#pragma unroll
    for (int i = 1; i < 12; i++) mx = fmaxf(mx, lg[i]);
    float sum = 0.f;
#pragma unroll
    for (int i = 0; i < 12; i++) { lg[i] = __expf(lg[i] - mx); sum += lg[i]; }
    const float inv = 1.f / sum;
    const int b = row >> 13;
    const int Hs[3] = {60, 30, 15}, Ws[3] = {80, 40, 20}, St[3] = {0, 4800, 6000};
#pragma unroll
    for (int p = 0; p < 12; p++) {
      const int l = p >> 2;
      const int W = Ws[l], H = Hs[l];
      const float gx = Rx[l] * W + off[p * 2]     - 0.5f;
      const float gy = Ry[l] * H + off[p * 2 + 1] - 0.5f;
      const float x0f = floorf(gx), y0f = floorf(gy);
      const float wx = gx - x0f, wy = gy - y0f;
      const int x0 = (int)x0f, y0 = (int)y0f;
      const float aw = lg[p] * inv;
      float cw[4] = {(1.f - wx) * (1.f - wy), wx * (1.f - wy),
                     (1.f - wx) * wy, wx * wy};
      const int base = b * 6300 + St[l];
      int ci[4];
#pragma unroll
      for (int k = 0; k < 4; k++) {
        const int xx = x0 + (k & 1), yy = y0 + (k >> 1);
        const bool valid = (xx >= 0) & (xx < W) & (yy >= 0) & (yy < H);
        const int xc = min(max(xx, 0), W - 1);
        const int yc = min(max(yy, 0), H - 1);
        ci[k] = ((base + yc * W + xc) << 8) + h * 32;
        cw[k] = valid ? cw[k] * aw : 0.f;
      }
      sIdx[t * 12 + p] = make_int4(ci[0], ci[1], ci[2], ci[3]);
      s16x4 wv; wv.x = f2b(cw[0]); wv.y = f2b(cw[1]); wv.z = f2b(cw[2]); wv.w = f2b(cw[3]);
      sW[t * 12 + p] = wv;
    }
  }
  __syncthreads();

  const int lu = t >> 2, c4 = (t & 3) * 8;
  float acc[8];
#pragma unroll
  for (int i = 0; i < 8; i++) acc[i] = 0.f;
#pragma unroll 2
  for (int p = 0; p < 12; p++) {
    const int4 idx = sIdx[lu * 12 + p];
    const s16x4 wb = sW[lu * 12 + p];
    const float w0 = b2f(wb.x), w1 = b2f(wb.y), w2 = b2f(wb.z), w3 = b2f(wb.w);
    const short8 v0 = *(const short8*)(vproj + idx.x + c4);
    const short8 v1 = *(const short8*)(vproj + idx.y + c4);
    const short8 v2 = *(const short8*)(vproj + idx.z + c4);
    const short8 v3 = *(const short8*)(vproj + idx.w + c4);
    float f0[8], f1[8], f2[8], f3[8];
    b8f(v0, f0); b8f(v1, f1); b8f(v2, f2); b8f(v3, f3);
#pragma unroll
    for (int j = 0; j < 8; j++)
      acc[j] += w0 * f0[j] + w1 * f1[j] + w2 * f2[j] + w3 * f3[j];
  }
  short8 o;
#pragma unroll
  for (int j = 0; j < 8; j++) o[j] = f2b(acc[j]);
  *(short8*)(out + (size_t)(blockIdx.x * 256 + t) * 8) = o;
}

// ---------------------------------------------------------------------------
// Launch
// ---------------------------------------------------------------------------
extern "C" void kernel_launch(void* const* d_in, const int* in_sizes, int n_in,
                              void* d_out, int out_size, void* d_ws, size_t ws_size,
                              hipStream_t stream)
{
  const float* query     = (const float*)d_in[0];
  const float* value     = (const float*)d_in[1];
  const float* query_pos = (const float*)d_in[2];
  const float* ref_pts   = (const float*)d_in[3];
  const float* g1  = (const float*)d_in[6];
  const float* b1  = (const float*)d_in[7];
  const float* Wo  = (const float*)d_in[8];
  const float* bo  = (const float*)d_in[9];
  const float* Wa  = (const float*)d_in[10];
  const float* ba  = (const float*)d_in[11];
  const float* Wv  = (const float*)d_in[12];
  const float* bv  = (const float*)d_in[13];
  const float* Wp  = (const float*)d_in[14];
  const float* bp  = (const float*)d_in[15];
  const float* g2  = (const float*)d_in[16];
  const float* b2  = (const float*)d_in[17];
  const float* Wf1 = (const float*)d_in[18];
  const float* bf1 = (const float*)d_in[19];
  const float* Wf2 = (const float*)d_in[20];
  const float* bf2 = (const float*)d_in[21];

  char* ws = (char*)d_ws;
  short* wt_oa   = (short*)(ws + 0);          // 384x256 bf16
  short* wt_v    = (short*)(ws + 196608);
  short* wt_p    = (short*)(ws + 327680);
  short* wt_f1   = (short*)(ws + 458752);
  short* wt_f2   = (short*)(ws + 983040);
  short* qnb     = (short*)(ws + 1507328);    // 16384x256 bf16 (LN1, no pos)
  short* qa      = (short*)(ws + 18284544);   // 16384x256 bf16 (later q2)
  float* oabuf   = (float*)(ws + 26673152);   // 16384x288 f32 (dead after gather)
  short* vproj   = (short*)(ws + 45547520);   // 12600x256 bf16
  short* sampled = (short*)(ws + 51998720);   // 16384x256 bf16
  float* qbuf    = (float*)(ws + 60387328);   // 16384x256 f32
  short* valbf   = (short*)(ws + 77164544);   // 12672x256 bf16
  short* q2      = qa;                        // reuse (qa dead after oa GEMM)
  short* hidden  = (short*)(ws + 26673152);   // 16384x1024 bf16 over oabuf+vproj+sampled
  float* outp = (float*)d_out;

  // 1. merged: weight convert + value convert + LN1
  prep_all<<<9057, 256, 0, stream>>>(Wo, Wa, Wv, Wp, Wf1, Wf2,
                                     wt_oa, wt_v, wt_p, wt_f1, wt_f2,
                                     value, valbf, query, query_pos,
                                     g1, b1, qnb, qa);
  // 2. merged GEMMs: oa = qa@[Wo|Wa]+[bo|ba] (f32) ; vproj = value@Wv+bv (bf16)
  gemm_oa_v<<<582, 256, 0, stream>>>(qa, wt_oa, bo, ba, oabuf,
                                     valbf, wt_v, bv, vproj);
  // 3. fused prep+gather -> sampled bf16 [16384x256]
  deform_fused<<<2048, 256, 0, stream>>>(vproj, oabuf, ref_pts, sampled);
  // 4. qbuf = sampled @ Wp + bp + b2f(qnb) + query   f32
  gemm_k<2><<<dim3(2, 128), 256, 0, stream>>>(sampled, wt_p, bp, nullptr, qnb,
                                              query, qbuf, 16384, 256, 256, 256);
  // 5. q2 = LN(qbuf) bf16
  ln_kernel<<<4096, 256, 0, stream>>>(qbuf, g2, b2, q2);
  // 6. hidden = gelu(q2 @ Wf1 + bf1) bf16   [16384 x 1024]
  gemm_k<1><<<dim3(8, 128), 256, 0, stream>>>(q2, wt_f1, bf1, nullptr, nullptr,
                                              nullptr, hidden, 16384, 1024, 1024, 256);
  // 7. out = qbuf + hidden @ Wf2 + bf2   f32
  gemm_k<3><<<dim3(2, 128), 256, 0, stream>>>(hidden, wt_f2, bf2, nullptr, qbuf,
                                              nullptr, outp, 16384, 256, 256, 1024);
}